// Round 1
// baseline (125.150 us; speedup 1.0000x reference)
//
#include <hip/hip_runtime.h>
#include <hip/hip_bf16.h>
#include <math.h>

// NT-Xent loss, N=4096, D=256.
// loss = (1/2N) * sum_i [ 2 + log( sum_{j != i} exp(2*dot(zn_i,zn_j) - 2) ) - 2*dot(zn_i, zn_pair(i)) ]
// K1: normalize rows of concat(zi,zj) -> bf16 zn in ws; zero d_out.
// K2: 128x128-tile bf16 MFMA GEMM of zn * zn^T with fused exp(s-2) row-sum epilogue;
//     per-(colblock,row) partials written to ws (no global atomics).
// K3: per-row: sum 64 partials, subtract diagonal exp, add positive-pair term, reduce.

using short8  = __attribute__((ext_vector_type(8))) short;
using floatx4 = __attribute__((ext_vector_type(4))) float;

constexpr int TWO_N = 8192;
constexpr int DIM   = 256;
constexpr int NBLK  = 64;      // 8192 / 128 tiles per side

__device__ static inline unsigned short f2bf(float f) {
  unsigned u = __float_as_uint(f);
  return (unsigned short)((u + 0x7fffu + ((u >> 16) & 1u)) >> 16);  // RNE
}

__device__ static inline void async_copy16(const __hip_bfloat16* g, __hip_bfloat16* l) {
  __builtin_amdgcn_global_load_lds(
      (const __attribute__((address_space(1))) void*)(const void*)g,
      (__attribute__((address_space(3))) void*)(void*)l, 16, 0, 0);
}

// ---------------- K1: normalize + cast to bf16 ----------------
__global__ __launch_bounds__(256) void k_normalize(
    const float* __restrict__ zi, const float* __restrict__ zj,
    __hip_bfloat16* __restrict__ zn, float* __restrict__ out)
{
  if (blockIdx.x == 0 && threadIdx.x == 0) out[0] = 0.0f;
  const int lane = threadIdx.x & 63;
  const int wave = threadIdx.x >> 6;
  const int row  = blockIdx.x * 4 + wave;
  const float* src = (row < 4096) ? (zi + (size_t)row * DIM)
                                  : (zj + (size_t)(row - 4096) * DIM);
  float4 v = reinterpret_cast<const float4*>(src)[lane];
  float ss = v.x * v.x + v.y * v.y + v.z * v.z + v.w * v.w;
#pragma unroll
  for (int m = 32; m >= 1; m >>= 1) ss += __shfl_xor(ss, m, 64);
  float inv = 1.0f / fmaxf(sqrtf(ss), 1e-8f);
  ushort4 o;
  o.x = f2bf(v.x * inv); o.y = f2bf(v.y * inv);
  o.z = f2bf(v.z * inv); o.w = f2bf(v.w * inv);
  reinterpret_cast<ushort4*>(zn + (size_t)row * DIM)[lane] = o;
}

// ---------------- K2: GEMM + exp row-sum epilogue ----------------
// grid (jb=64, ib=64), block 256 = 4 waves in 2x2; each wave owns a 64x64 subtile
// (4x4 grid of 16x16x32 MFMA accumulators). LDS tiles As/Bs are [128][32] bf16 with
// the 16B k-slot XOR-swizzled by (row>>1)&3 so ds_read_b128 fragment reads are
// 2-way-per-bank (free) instead of 8-way.
__global__ __launch_bounds__(256) void k_simexp(
    const __hip_bfloat16* __restrict__ Z, float* __restrict__ partial)
{
  __shared__ __align__(16) __hip_bfloat16 As[128 * 32];
  __shared__ __align__(16) __hip_bfloat16 Bs[128 * 32];
  __shared__ float rowsum[128];

  const int tid  = threadIdx.x;
  const int lane = tid & 63;
  const int wave = tid >> 6;
  const int wm   = wave >> 1;   // 0..1 row half
  const int wn   = wave & 1;    // 0..1 col half

  const int jb = blockIdx.x;
  const int ib = blockIdx.y;
  const int i0 = ib * 128;
  const int j0 = jb * 128;

  if (tid < 128) rowsum[tid] = 0.0f;

  floatx4 acc[4][4] = {};

  // staging: 16 one-KB wave-calls per K-iter (8 A segs + 8 B segs), 4 per wave.
  // lane -> subrow = lane>>2 (16 rows/call), loads swizzled global k-slot.
  const int subrow = lane >> 2;
  const int col8   = (lane & 3) ^ ((lane >> 3) & 3);  // swizzled 16B slot to fetch
  const int q      = lane >> 4;                       // logical k8 for fragments

  for (int kk = 0; kk < 8; ++kk) {
    const int k0 = kk * 32;
#pragma unroll
    for (int c = 0; c < 4; ++c) {
      const int t   = wave * 4 + c;        // 0..15
      const int seg = t & 7;
      const int grow = ((t < 8) ? i0 : j0) + seg * 16 + subrow;
      const __hip_bfloat16* gp = Z + (size_t)grow * DIM + k0 + col8 * 8;
      __hip_bfloat16* lp = ((t < 8) ? As : Bs) + seg * 512;  // + lane*16B implicit
      async_copy16(gp, lp);
    }
    __syncthreads();

    short8 a[4], b[4];
#pragma unroll
    for (int mt = 0; mt < 4; ++mt) {
      const int r    = wm * 64 + mt * 16 + (lane & 15);
      const int slot = q ^ ((r >> 1) & 3);
      a[mt] = *reinterpret_cast<const short8*>(As + r * 32 + slot * 8);
    }
#pragma unroll
    for (int nt = 0; nt < 4; ++nt) {
      const int r    = wn * 64 + nt * 16 + (lane & 15);
      const int slot = q ^ ((r >> 1) & 3);
      b[nt] = *reinterpret_cast<const short8*>(Bs + r * 32 + slot * 8);
    }
#pragma unroll
    for (int mt = 0; mt < 4; ++mt)
#pragma unroll
      for (int nt = 0; nt < 4; ++nt)
        acc[mt][nt] = __builtin_amdgcn_mfma_f32_16x16x32_bf16(
            a[mt], b[nt], acc[mt][nt], 0, 0, 0);
    __syncthreads();
  }

  // epilogue: e = exp(2*dot - 2); sum over this wave's 64 cols per row.
  // C/D layout: col = lane&15, row = q*4 + reg.
#pragma unroll
  for (int mt = 0; mt < 4; ++mt) {
#pragma unroll
    for (int reg = 0; reg < 4; ++reg) {
      float s = 0.0f;
#pragma unroll
      for (int nt = 0; nt < 4; ++nt)
        s += __expf(2.0f * acc[mt][nt][reg] - 2.0f);
      s += __shfl_xor(s, 1, 64);
      s += __shfl_xor(s, 2, 64);
      s += __shfl_xor(s, 4, 64);
      s += __shfl_xor(s, 8, 64);
      if ((lane & 15) == 0) {
        const int r = wm * 64 + mt * 16 + q * 4 + reg;
        atomicAdd(&rowsum[r], s);
      }
    }
  }
  __syncthreads();
  if (tid < 128)
    partial[(size_t)jb * TWO_N + i0 + tid] = rowsum[tid];
}

// ---------------- K3: finalize ----------------
// one wave per row; lane = column-block index for partials, lane*4 = dim offset for dots.
__global__ __launch_bounds__(256) void k_finalize(
    const __hip_bfloat16* __restrict__ Z, const float* __restrict__ partial,
    float* __restrict__ out)
{
  __shared__ float wsum[4];
  const int lane = threadIdx.x & 63;
  const int wave = threadIdx.x >> 6;
  float acc = 0.0f;
#pragma unroll
  for (int it = 0; it < 4; ++it) {
    const int row = blockIdx.x * 16 + it * 4 + wave;
    const int pr  = (row < 4096) ? row + 4096 : row - 4096;
    float p = partial[(size_t)lane * TWO_N + row];
    ushort4 ua = reinterpret_cast<const ushort4*>(Z + (size_t)row * DIM)[lane];
    ushort4 ub = reinterpret_cast<const ushort4*>(Z + (size_t)pr  * DIM)[lane];
    float a0 = __uint_as_float((unsigned)ua.x << 16);
    float a1 = __uint_as_float((unsigned)ua.y << 16);
    float a2 = __uint_as_float((unsigned)ua.z << 16);
    float a3 = __uint_as_float((unsigned)ua.w << 16);
    float b0 = __uint_as_float((unsigned)ub.x << 16);
    float b1 = __uint_as_float((unsigned)ub.y << 16);
    float b2 = __uint_as_float((unsigned)ub.z << 16);
    float b3 = __uint_as_float((unsigned)ub.w << 16);
    float sd = a0 * a0 + a1 * a1 + a2 * a2 + a3 * a3;  // self dot (bf16-rounded)
    float pd = a0 * b0 + a1 * b1 + a2 * b2 + a3 * b3;  // positive-pair dot
#pragma unroll
    for (int m = 32; m >= 1; m >>= 1) {
      p  += __shfl_xor(p,  m, 64);
      sd += __shfl_xor(sd, m, 64);
      pd += __shfl_xor(pd, m, 64);
    }
    if (lane == 0) {
      float se = p - __expf(2.0f * sd - 2.0f);   // remove diagonal term
      acc += 2.0f + __logf(se) - 2.0f * pd;
    }
  }
  if (lane == 0) wsum[wave] = acc;
  __syncthreads();
  if (threadIdx.x == 0)
    atomicAdd(out, (wsum[0] + wsum[1] + wsum[2] + wsum[3]) * (1.0f / (float)TWO_N));
}

// ---------------- launch ----------------
extern "C" void kernel_launch(void* const* d_in, const int* in_sizes, int n_in,
                              void* d_out, int out_size, void* d_ws, size_t ws_size,
                              hipStream_t stream) {
  const float* zi = (const float*)d_in[0];
  const float* zj = (const float*)d_in[1];
  float* out = (float*)d_out;

  __hip_bfloat16* zn = (__hip_bfloat16*)d_ws;                       // 8192*256*2 = 4 MB
  float* partial = (float*)((char*)d_ws + (size_t)TWO_N * DIM * 2); // 64*8192*4 = 2 MB

  k_normalize<<<dim3(TWO_N / 4), dim3(256), 0, stream>>>(zi, zj, zn, out);
  k_simexp<<<dim3(NBLK, NBLK), dim3(256), 0, stream>>>(zn, partial);
  k_finalize<<<dim3(512), dim3(256), 0, stream>>>(zn, partial, out);
}

// Round 2
// 103.754 us; speedup vs baseline: 1.2062x; 1.2062x over previous
//
#include <hip/hip_runtime.h>
#include <hip/hip_bf16.h>
#include <math.h>

// NT-Xent loss, N=4096, D=256, symmetric-GEMM version.
// loss = (1/2N) * sum_i [ 2 + log( sum_{j != i} exp(2*dot_ij - 2) ) - 2*dot(zn_i, zn_pair(i)) ]
// K1: normalize rows -> bf16 zn in ws; zero rowtotal[8192] and out.
// K2: upper-triangular 128x128 bf16 MFMA tiles (2080 blocks). Fused epilogue:
//     exp row-sums -> rowtotal[i] (global atomics), exp col-sums -> rowtotal[j]
//     (symmetry), diag tiles skip self-sim exactly, pair tiles (jb==ib+32)
//     accumulate the -2*pair_dot loss terms directly into out.
// K3: 32 blocks: loss += sum_i (2 + log(rowtotal[i])) / 2N.

using short8  = __attribute__((ext_vector_type(8))) short;
using floatx4 = __attribute__((ext_vector_type(4))) float;

constexpr int TWO_N = 8192;
constexpr int DIM   = 256;
constexpr int NB    = 64;                 // 8192/128 tile blocks per side
constexpr int NTRI  = NB * (NB + 1) / 2;  // 2080
constexpr float INV2N = 1.0f / 8192.0f;

__device__ static inline unsigned short f2bf(float f) {
  unsigned u = __float_as_uint(f);
  return (unsigned short)((u + 0x7fffu + ((u >> 16) & 1u)) >> 16);  // RNE
}

__device__ static inline void async_copy16(const __hip_bfloat16* g, __hip_bfloat16* l) {
  __builtin_amdgcn_global_load_lds(
      (const __attribute__((address_space(1))) void*)(const void*)g,
      (__attribute__((address_space(3))) void*)(void*)l, 16, 0, 0);
}

// ---------------- K1: normalize + cast to bf16, zero accumulators ----------------
__global__ __launch_bounds__(256) void k_normalize(
    const float* __restrict__ zi, const float* __restrict__ zj,
    __hip_bfloat16* __restrict__ zn, float* __restrict__ rowtotal,
    float* __restrict__ out)
{
  if (blockIdx.x == 0 && threadIdx.x == 0) out[0] = 0.0f;
  if (blockIdx.x < 32) rowtotal[blockIdx.x * 256 + threadIdx.x] = 0.0f;

  const int lane = threadIdx.x & 63;
  const int wave = threadIdx.x >> 6;
  const int row  = blockIdx.x * 4 + wave;
  const float* src = (row < 4096) ? (zi + (size_t)row * DIM)
                                  : (zj + (size_t)(row - 4096) * DIM);
  float4 v = reinterpret_cast<const float4*>(src)[lane];
  float ss = v.x * v.x + v.y * v.y + v.z * v.z + v.w * v.w;
#pragma unroll
  for (int m = 32; m >= 1; m >>= 1) ss += __shfl_xor(ss, m, 64);
  float inv = 1.0f / fmaxf(sqrtf(ss), 1e-8f);
  ushort4 o;
  o.x = f2bf(v.x * inv); o.y = f2bf(v.y * inv);
  o.z = f2bf(v.z * inv); o.w = f2bf(v.w * inv);
  reinterpret_cast<ushort4*>(zn + (size_t)row * DIM)[lane] = o;
}

// ---------------- K2: triangular GEMM + fused exp/row/col-sum epilogue ----------------
// block 256 = 4 waves in 2x2; wave owns 64x64 (4x4 of 16x16x32 accumulators).
// LDS tiles [128][64] bf16 with 16B-slot XOR swizzle: phys_slot = logical ^ (row&7).
__global__ __launch_bounds__(256) void k_simexp(
    const __hip_bfloat16* __restrict__ Z, float* __restrict__ rowtotal,
    float* __restrict__ out)
{
  __shared__ __align__(16) __hip_bfloat16 As[128 * 64];
  __shared__ __align__(16) __hip_bfloat16 Bs[128 * 64];
  __shared__ float rowsum[128];
  __shared__ float colsum[128];

  const int tid  = threadIdx.x;
  const int lane = tid & 63;
  const int wave = tid >> 6;
  const int wm   = wave >> 1;   // output row half
  const int wn   = wave & 1;    // output col half

  // triangular decode: blockIdx.x -> (ib <= jb)
  const int u = blockIdx.x;
  int jb = (int)((sqrtf(8.0f * (float)u + 1.0f) - 1.0f) * 0.5f);
  while ((jb + 1) * (jb + 2) / 2 <= u) ++jb;
  while (jb * (jb + 1) / 2 > u) --jb;
  const int ib = u - jb * (jb + 1) / 2;

  const bool diagblk = (ib == jb);
  const bool pairblk = (jb == ib + 32);
  const int i0 = ib * 128;
  const int j0 = jb * 128;

  if (tid < 128) { rowsum[tid] = 0.0f; colsum[tid] = 0.0f; }

  floatx4 acc[4][4] = {};

  const int lane7 = lane & 7;
  const int sub   = lane >> 3;               // 0..7 subrow within 8-row segment
  const int gkoff = ((lane7 ^ sub) << 3);    // swizzled logical 16B slot to fetch
  const int q     = lane >> 4;               // 0..3
  const int c16   = lane & 15;

  // staging bases: waves 0,1 -> As (rows 0..63 / 64..127), waves 2,3 -> Bs
  const __hip_bfloat16* gbase =
      Z + (size_t)((wave < 2 ? i0 : j0) + (wave & 1) * 64) * DIM;
  __hip_bfloat16* lbase = ((wave < 2) ? As : Bs) + (wave & 1) * 64 * 64;

  for (int kk = 0; kk < 4; ++kk) {
    const int k0 = kk * 64;
#pragma unroll
    for (int c = 0; c < 8; ++c) {
      const __hip_bfloat16* gp = gbase + (size_t)(c * 8 + sub) * DIM + k0 + gkoff;
      async_copy16(gp, lbase + c * 512);   // + lane*16B implicit
    }
    __syncthreads();

#pragma unroll
    for (int ks = 0; ks < 2; ++ks) {
      const int phys = (ks * 4 + q) ^ lane7;  // physical 16B slot for this lane
      short8 a[4], b[4];
#pragma unroll
      for (int mt = 0; mt < 4; ++mt)
        a[mt] = *reinterpret_cast<const short8*>(
            As + (wm * 64 + mt * 16 + c16) * 64 + phys * 8);
#pragma unroll
      for (int nt = 0; nt < 4; ++nt)
        b[nt] = *reinterpret_cast<const short8*>(
            Bs + (wn * 64 + nt * 16 + c16) * 64 + phys * 8);
#pragma unroll
      for (int mt = 0; mt < 4; ++mt)
#pragma unroll
        for (int nt = 0; nt < 4; ++nt)
          acc[mt][nt] = __builtin_amdgcn_mfma_f32_16x16x32_bf16(
              a[mt], b[nt], acc[mt][nt], 0, 0, 0);
    }
    __syncthreads();
  }

  // ---- epilogue ----
  // C/D layout: col = lane&15 (within nt-tile), row = q*4 + reg (within mt-tile).
  float colacc[4] = {0.f, 0.f, 0.f, 0.f};
  float pc = 0.f;
  const bool diagwave = (wm == wn);

#pragma unroll
  for (int mt = 0; mt < 4; ++mt) {
#pragma unroll
    for (int reg = 0; reg < 4; ++reg) {
      const bool onquad = (c16 == q * 4 + reg);  // lane holds a subtile-diag elem
      float s = 0.0f;
#pragma unroll
      for (int nt = 0; nt < 4; ++nt) {
        float e = __expf(2.0f * acc[mt][nt][reg] - 2.0f);
        bool skip = diagblk && diagwave && (nt == mt) && onquad;  // true self-sim
        s += skip ? 0.0f : e;
        colacc[nt] += e;
      }
      if (pairblk && diagwave && onquad) pc += acc[mt][mt][reg];  // pair dot
      s += __shfl_xor(s, 1, 64);
      s += __shfl_xor(s, 2, 64);
      s += __shfl_xor(s, 4, 64);
      s += __shfl_xor(s, 8, 64);
      if (c16 == 0)
        atomicAdd(&rowsum[wm * 64 + mt * 16 + q * 4 + reg], s);
    }
  }

  if (!diagblk) {
#pragma unroll
    for (int nt = 0; nt < 4; ++nt) {
      float cs = colacc[nt];
      cs += __shfl_xor(cs, 16, 64);
      cs += __shfl_xor(cs, 32, 64);
      if (lane < 16) atomicAdd(&colsum[wn * 64 + nt * 16 + lane], cs);
    }
  }

  if (pairblk && diagwave) {
#pragma unroll
    for (int m = 32; m >= 1; m >>= 1) pc += __shfl_xor(pc, m, 64);
    // each pair diag elem covers rows i and i+4096: loss += -2*(2*dot) per pair
    if (lane == 0) atomicAdd(out, -4.0f * pc * INV2N);
  }

  __syncthreads();
  if (tid < 128) {
    atomicAdd(&rowtotal[i0 + tid], rowsum[tid]);
    if (!diagblk) atomicAdd(&rowtotal[j0 + tid], colsum[tid]);
  }
}

// ---------------- K3: finalize (logs + reduce) ----------------
__global__ __launch_bounds__(256) void k_finalize(
    const float* __restrict__ rowtotal, float* __restrict__ out)
{
  __shared__ float wsum[4];
  const int lane = threadIdx.x & 63;
  const int wave = threadIdx.x >> 6;
  const int row  = blockIdx.x * 256 + threadIdx.x;
  float v = 2.0f + __logf(rowtotal[row]);
#pragma unroll
  for (int m = 32; m >= 1; m >>= 1) v += __shfl_xor(v, m, 64);
  if (lane == 0) wsum[wave] = v;
  __syncthreads();
  if (threadIdx.x == 0)
    atomicAdd(out, (wsum[0] + wsum[1] + wsum[2] + wsum[3]) * INV2N);
}

// ---------------- launch ----------------
extern "C" void kernel_launch(void* const* d_in, const int* in_sizes, int n_in,
                              void* d_out, int out_size, void* d_ws, size_t ws_size,
                              hipStream_t stream) {
  const float* zi = (const float*)d_in[0];
  const float* zj = (const float*)d_in[1];
  float* out = (float*)d_out;

  __hip_bfloat16* zn = (__hip_bfloat16*)d_ws;                        // 8192*256*2 = 4 MB
  float* rowtotal = (float*)((char*)d_ws + (size_t)TWO_N * DIM * 2); // 8192*4 = 32 KB

  k_normalize<<<dim3(TWO_N / 4), dim3(256), 0, stream>>>(zi, zj, zn, rowtotal, out);
  k_simexp<<<dim3(NTRI), dim3(256), 0, stream>>>(zn, rowtotal, out);
  k_finalize<<<dim3(TWO_N / 256), dim3(256), 0, stream>>>(rowtotal, out);
}